// Round 1
// baseline (644.160 us; speedup 1.0000x reference)
//
#include <hip/hip_runtime.h>
#include <math.h>

#define NEG_SLOPE 0.2f

__device__ __forceinline__ float lrelu(float x) { return x > 0.f ? x : NEG_SLOPE * x; }
__device__ __forceinline__ float eluf(float x) { return x > 0.f ? x : expm1f(x); }

// ---------------- SGEMM: C[M,N] = A[M,K] @ B[K,N], fp32. Requires N%64==0, K%16==0.
__global__ __launch_bounds__(256) void sgemm64(const float* __restrict__ A,
                                               const float* __restrict__ B,
                                               float* __restrict__ C,
                                               int M, int N, int K) {
  __shared__ float As[16][64];
  __shared__ float Bs[16][64];
  const int tid = threadIdx.x;
  const int tx = tid & 15, ty = tid >> 4;
  const int row0 = blockIdx.x * 64;
  const int col0 = blockIdx.y * 64;
  const int arow = tid >> 2, acol = (tid & 3) << 2;
  const int brow = tid >> 4, bcol = (tid & 15) << 2;
  float acc[4][4] = {};
  for (int kk = 0; kk < K; kk += 16) {
    float4 av = make_float4(0.f, 0.f, 0.f, 0.f);
    if (row0 + arow < M) av = *(const float4*)(A + (size_t)(row0 + arow) * K + kk + acol);
    As[acol + 0][arow] = av.x;
    As[acol + 1][arow] = av.y;
    As[acol + 2][arow] = av.z;
    As[acol + 3][arow] = av.w;
    *(float4*)(&Bs[brow][bcol]) = *(const float4*)(B + (size_t)(kk + brow) * N + col0 + bcol);
    __syncthreads();
#pragma unroll
    for (int k = 0; k < 16; ++k) {
      float a[4], b[4];
#pragma unroll
      for (int i = 0; i < 4; ++i) a[i] = As[k][ty * 4 + i];
#pragma unroll
      for (int j = 0; j < 4; ++j) b[j] = Bs[k][tx * 4 + j];
#pragma unroll
      for (int i = 0; i < 4; ++i)
#pragma unroll
        for (int j = 0; j < 4; ++j) acc[i][j] = fmaf(a[i], b[j], acc[i][j]);
    }
    __syncthreads();
  }
#pragma unroll
  for (int i = 0; i < 4; ++i) {
    int r = row0 + ty * 4 + i;
    if (r < M) {
#pragma unroll
      for (int j = 0; j < 4; ++j) C[(size_t)r * N + col0 + tx * 4 + j] = acc[i][j];
    }
  }
}

// ---------------- el/er: el[n][h] = sum_d feat[n][h*32+d]*al[h*32+d]. One wave per node.
__global__ __launch_bounds__(256) void compute_elr(const float* __restrict__ feat,
                                                   const float* __restrict__ al,
                                                   const float* __restrict__ ar,
                                                   float* __restrict__ el,
                                                   float* __restrict__ er, int N) {
  int wave = threadIdx.x >> 6, lane = threadIdx.x & 63;
  int n = blockIdx.x * 4 + wave;
  if (n >= N) return;
  float4 f = *(const float4*)(feat + (size_t)n * 256 + lane * 4);
  float4 a = *(const float4*)(al + lane * 4);
  float4 b = *(const float4*)(ar + lane * 4);
  float sl = f.x * a.x + f.y * a.y + f.z * a.z + f.w * a.w;
  float sr = f.x * b.x + f.y * b.y + f.z * b.z + f.w * b.w;
#pragma unroll
  for (int d = 1; d < 8; d <<= 1) {
    sl += __shfl_xor(sl, d);
    sr += __shfl_xor(sr, d);
  }
  if ((lane & 7) == 0) {
    el[n * 8 + (lane >> 3)] = sl;
    er[n * 8 + (lane >> 3)] = sr;
  }
}

// ---------------- CSR build
__global__ void deg_count(const int* __restrict__ dst, int* __restrict__ deg, int E) {
  int i = blockIdx.x * blockDim.x + threadIdx.x;
  if (i < E) atomicAdd(&deg[dst[i]], 1);
}

__global__ __launch_bounds__(256) void scan1(const int* __restrict__ deg, int* __restrict__ offs,
                                             int* __restrict__ bsums, int n) {
  __shared__ int sh[256];
  int i = blockIdx.x * 256 + threadIdx.x;
  int v = (i < n) ? deg[i] : 0;
  sh[threadIdx.x] = v;
  __syncthreads();
  for (int d = 1; d < 256; d <<= 1) {
    int t = (threadIdx.x >= d) ? sh[threadIdx.x - d] : 0;
    __syncthreads();
    sh[threadIdx.x] += t;
    __syncthreads();
  }
  if (i < n) offs[i + 1] = sh[threadIdx.x];
  if (threadIdx.x == 255) bsums[blockIdx.x] = sh[255];
  if (i == 0) offs[0] = 0;
}

__global__ __launch_bounds__(256) void scan2(int* __restrict__ bsums, int nb) {
  __shared__ int sh[256];
  int t = threadIdx.x;
  int v = (t < nb) ? bsums[t] : 0;
  sh[t] = v;
  __syncthreads();
  for (int d = 1; d < 256; d <<= 1) {
    int tmp = (t >= d) ? sh[t - d] : 0;
    __syncthreads();
    sh[t] += tmp;
    __syncthreads();
  }
  if (t < nb) bsums[t] = (t == 0) ? 0 : sh[t - 1];
}

__global__ __launch_bounds__(256) void scan3(int* __restrict__ offs, const int* __restrict__ bsums,
                                             int n) {
  int i = blockIdx.x * 256 + threadIdx.x;
  if (i < n) offs[i + 1] += bsums[blockIdx.x];
}

__global__ void scatter_edges(const int* __restrict__ src, const int* __restrict__ dst,
                              int* __restrict__ cursor, int* __restrict__ csrc, int E) {
  int i = blockIdx.x * blockDim.x + threadIdx.x;
  if (i < E) {
    int d = dst[i];
    int pos = atomicAdd(&cursor[d], 1);
    csrc[pos] = src[i];
  }
}

// ---------------- GAT aggregation: one wave per dst node.
// mode 0: hout[n] = elu(rst + bias (+hres))       (layer 1: hres==null)
// mode 1: accumulate elu(rst + hres + bias) into per-block column sums -> partial[block][256]
__global__ __launch_bounds__(256) void gat_agg(const int* __restrict__ offs,
                                               const int* __restrict__ csrc,
                                               const float* __restrict__ feat,
                                               const float* __restrict__ el,
                                               const float* __restrict__ er,
                                               const float* __restrict__ bias,
                                               const float* __restrict__ hres,
                                               float* __restrict__ hout,
                                               float* __restrict__ partial, int N, int mode) {
  __shared__ float psum[4][256];
  const int wave = threadIdx.x >> 6;
  const int lane = threadIdx.x & 63;
  const int hh = lane & 7;       // head for softmax phases
  const int myh = lane >> 3;     // head owning my features (lane*4 .. lane*4+3)
  float4 bvec = *(const float4*)(bias + lane * 4);
  float t0 = 0.f, t1 = 0.f, t2 = 0.f, t3 = 0.f;

  for (int n = blockIdx.x * 4 + wave; n < N; n += gridDim.x * 4) {
    const int o0 = offs[n];
    const int deg = offs[n + 1] - o0;
    const float er_h = er[n * 8 + hh];

    // ---- phase 1: online softmax stats; lanes = 8 edge-slots x 8 heads
    float m = -1e30f, ssum = 0.f;
    for (int base = 0; base < deg; base += 8) {
      int idx = base + (lane >> 3);
      if (idx < deg) {
        int s = csrc[o0 + idx];
        float e = lrelu(el[s * 8 + hh] + er_h);
        float mn = fmaxf(m, e);
        ssum = ssum * __expf(m - mn) + __expf(e - mn);
        m = mn;
      }
    }
#pragma unroll
    for (int d = 8; d < 64; d <<= 1) {
      float mo = __shfl_xor(m, d);
      float so = __shfl_xor(ssum, d);
      float mn = fmaxf(m, mo);
      ssum = ssum * __expf(m - mn) + so * __expf(mo - mn);
      m = mn;
    }
    float inv_denom = (ssum > 0.f) ? 1.f / ssum : 0.f;

    // ---- phase 2: weighted gather-accumulate, one edge at a time (wave-wide float4 gather)
    float a0 = 0.f, a1 = 0.f, a2 = 0.f, a3 = 0.f;
    for (int base = 0; base < deg; base += 64) {
      int cnt = min(64, deg - base);
      int sreg = (base + lane < deg) ? csrc[o0 + base + lane] : 0;
      for (int j = 0; j < cnt; ++j) {
        int s = __shfl(sreg, j);
        // every lane computes alpha for head hh; I need head myh -> shuffle from lane myh
        float e = lrelu(el[s * 8 + hh] + er_h);
        float alpha = __expf(e - m) * inv_denom;
        float am = __shfl(alpha, myh);
        float4 f = *(const float4*)(feat + (size_t)s * 256 + lane * 4);
        a0 = fmaf(am, f.x, a0);
        a1 = fmaf(am, f.y, a1);
        a2 = fmaf(am, f.z, a2);
        a3 = fmaf(am, f.w, a3);
      }
    }

    // ---- epilogue
    float v0 = a0 + bvec.x, v1 = a1 + bvec.y, v2 = a2 + bvec.z, v3 = a3 + bvec.w;
    if (hres) {
      float4 r4 = *(const float4*)(hres + (size_t)n * 256 + lane * 4);
      v0 += r4.x; v1 += r4.y; v2 += r4.z; v3 += r4.w;
    }
    v0 = eluf(v0); v1 = eluf(v1); v2 = eluf(v2); v3 = eluf(v3);
    if (mode == 0) {
      float4 o = make_float4(v0, v1, v2, v3);
      *(float4*)(hout + (size_t)n * 256 + lane * 4) = o;
    } else {
      t0 += v0; t1 += v1; t2 += v2; t3 += v3;
    }
  }

  if (mode == 1) {
    psum[wave][lane * 4 + 0] = t0;
    psum[wave][lane * 4 + 1] = t1;
    psum[wave][lane * 4 + 2] = t2;
    psum[wave][lane * 4 + 3] = t3;
    __syncthreads();
    int t = threadIdx.x;
    partial[(size_t)blockIdx.x * 256 + t] = psum[0][t] + psum[1][t] + psum[2][t] + psum[3][t];
  }
}

// ---------------- reduce partial column sums -> s[256]
__global__ __launch_bounds__(256) void reduce_partials(const float* __restrict__ partial,
                                                       float* __restrict__ s, int rows) {
  int t = threadIdx.x;
  float acc = 0.f;
  for (int r = blockIdx.x; r < rows; r += gridDim.x) acc += partial[(size_t)r * 256 + t];
  atomicAdd(&s[t], acc);
}

// ---------------- out[c] = (s/N) @ Wl + bl
__global__ __launch_bounds__(128) void final_linear(const float* __restrict__ s,
                                                    const float* __restrict__ Wl,
                                                    const float* __restrict__ bl,
                                                    float* __restrict__ out, float invN) {
  int c = threadIdx.x;
  float acc = 0.f;
  for (int k = 0; k < 256; ++k) acc = fmaf(s[k], Wl[k * 128 + c], acc);
  out[c] = acc * invN + bl[c];
}

extern "C" void kernel_launch(void* const* d_in, const int* in_sizes, int n_in, void* d_out,
                              int out_size, void* d_ws, size_t ws_size, hipStream_t stream) {
  const float* x  = (const float*)d_in[0];
  const int* src  = (const int*)d_in[1];
  const int* dst  = (const int*)d_in[2];
  const float* W1 = (const float*)d_in[3];
  const float* al1 = (const float*)d_in[4];
  const float* ar1 = (const float*)d_in[5];
  const float* b1 = (const float*)d_in[6];
  const float* W2 = (const float*)d_in[7];
  const float* al2 = (const float*)d_in[8];
  const float* ar2 = (const float*)d_in[9];
  const float* b2 = (const float*)d_in[10];
  const float* Wl = (const float*)d_in[11];
  const float* bl = (const float*)d_in[12];
  float* out = (float*)d_out;

  const int N = in_sizes[0] / 128;  // 50000
  const int E = in_sizes[1];        // 800000
  const int AGG_BLOCKS = 2048;

  // ---- workspace carve (bytes)
  char* w = (char*)d_ws;
  float* feat = (float*)w;      w += (size_t)N * 256 * 4;   // 51.2 MB (feat1, then feat2)
  float* h1 = (float*)w;        w += (size_t)N * 256 * 4;   // 51.2 MB
  float* el = (float*)w;        w += (size_t)N * 8 * 4;
  float* er = (float*)w;        w += (size_t)N * 8 * 4;
  int* offs = (int*)w;          w += (size_t)(N + 64) * 4;
  int* deg = (int*)w;           w += (size_t)N * 4;
  int* cursor = (int*)w;        w += (size_t)N * 4;
  int* csrc = (int*)w;          w += (size_t)E * 4;
  int* bsums = (int*)w;         w += 256 * 4;
  float* partial = (float*)w;   w += (size_t)AGG_BLOCKS * 256 * 4;
  float* svec = (float*)w;      w += 256 * 4;

  const int nb = (N + 255) / 256;           // scan blocks (196)
  const int eb = (E + 255) / 256;           // edge blocks (3125)
  const int mb = (N + 63) / 64;             // gemm M blocks (782)
  const int nodeb = (N + 3) / 4;            // elr blocks (12500)

  // ---- CSR build
  hipMemsetAsync(deg, 0, (size_t)N * 4, stream);
  hipMemsetAsync(svec, 0, 256 * 4, stream);
  deg_count<<<eb, 256, 0, stream>>>(dst, deg, E);
  scan1<<<nb, 256, 0, stream>>>(deg, offs, bsums, N);
  scan2<<<1, 256, 0, stream>>>(bsums, nb);
  scan3<<<nb, 256, 0, stream>>>(offs, bsums, N);
  hipMemcpyAsync(cursor, offs, (size_t)N * 4, hipMemcpyDeviceToDevice, stream);
  scatter_edges<<<eb, 256, 0, stream>>>(src, dst, cursor, csrc, E);

  // ---- layer 1
  sgemm64<<<dim3(mb, 4), 256, 0, stream>>>(x, W1, feat, N, 256, 128);
  compute_elr<<<nodeb, 256, 0, stream>>>(feat, al1, ar1, el, er, N);
  gat_agg<<<AGG_BLOCKS, 256, 0, stream>>>(offs, csrc, feat, el, er, b1, nullptr, h1, nullptr, N, 0);

  // ---- layer 2 (feat buffer reused)
  sgemm64<<<dim3(mb, 4), 256, 0, stream>>>(h1, W2, feat, N, 256, 256);
  compute_elr<<<nodeb, 256, 0, stream>>>(feat, al2, ar2, el, er, N);
  gat_agg<<<AGG_BLOCKS, 256, 0, stream>>>(offs, csrc, feat, el, er, b2, h1, nullptr, partial, N, 1);

  // ---- mean over nodes, then final linear
  reduce_partials<<<64, 256, 0, stream>>>(partial, svec, AGG_BLOCKS);
  final_linear<<<1, 128, 0, stream>>>(svec, Wl, bl, out, 1.0f / (float)N);
}

// Round 2
// 442.112 us; speedup vs baseline: 1.4570x; 1.4570x over previous
//
#include <hip/hip_runtime.h>
#include <math.h>

#define NEG_SLOPE 0.2f

typedef __attribute__((ext_vector_type(8))) short short8;
typedef __attribute__((ext_vector_type(4))) float f32x4;

__device__ __forceinline__ float lrelu(float x) { return x > 0.f ? x : NEG_SLOPE * x; }
__device__ __forceinline__ float eluf(float x) { return x > 0.f ? x : expm1f(x); }
__device__ __forceinline__ unsigned short f2b(float f) {
  unsigned int u = __float_as_uint(f);
  u += 0x7FFFu + ((u >> 16) & 1u);  // RNE
  return (unsigned short)(u >> 16);
}
__device__ __forceinline__ float b2f(unsigned short h) {
  return __uint_as_float(((unsigned int)h) << 16);
}

// ---------------- casts
__global__ __launch_bounds__(256) void cast_bf16_vec(const float* __restrict__ in,
                                                     unsigned short* __restrict__ out, int n4) {
  int i = blockIdx.x * 256 + threadIdx.x;
  if (i < n4) {
    float4 v = *(const float4*)(in + (size_t)i * 4);
    ushort4 o;
    o.x = f2b(v.x); o.y = f2b(v.y); o.z = f2b(v.z); o.w = f2b(v.w);
    *(ushort4*)(out + (size_t)i * 4) = o;
  }
}

// W [K][N=256] fp32 -> Wt [N][K] bf16
__global__ __launch_bounds__(256) void cast_w_t(const float* __restrict__ W,
                                                unsigned short* __restrict__ Wt, int K) {
  int id = blockIdx.x * 256 + threadIdx.x;
  if (id < K * 256) {
    int k = id >> 8, n = id & 255;
    Wt[(size_t)n * K + k] = f2b(W[id]);
  }
}

// ---------------- bf16 MFMA GEMM: C[M][256] = A[M][K] @ B, B given transposed Bt[256][K].
#define BM 128
#define BN 64
#define BK 32
#define LDK 40
__global__ __launch_bounds__(256) void gemm_bf16(const unsigned short* __restrict__ A,
                                                 const unsigned short* __restrict__ Bt,
                                                 unsigned short* __restrict__ C, int M, int K) {
  __shared__ unsigned short As[BM][LDK];
  __shared__ unsigned short Bs[BN][LDK];
  const int tid = threadIdx.x;
  const int wave = tid >> 6, lane = tid & 63;
  const int quad = lane >> 4, l16 = lane & 15;
  const int row0 = blockIdx.x * BM;
  const int col0 = blockIdx.y * BN;

  f32x4 zero = {0.f, 0.f, 0.f, 0.f};
  f32x4 acc[2][4];
#pragma unroll
  for (int mt = 0; mt < 2; ++mt)
#pragma unroll
    for (int nt = 0; nt < 4; ++nt) acc[mt][nt] = zero;

  for (int kk = 0; kk < K; kk += BK) {
#pragma unroll
    for (int l = 0; l < 2; ++l) {
      int idx = tid + l * 256;
      int r = idx >> 2, ch = (idx & 3) * 8;
      short8 v = {};
      if (row0 + r < M) v = *(const short8*)(A + (size_t)(row0 + r) * K + kk + ch);
      *(short8*)&As[r][ch] = v;
    }
    {
      int n = tid >> 2, ch = (tid & 3) * 8;
      *(short8*)&Bs[n][ch] = *(const short8*)(Bt + (size_t)(col0 + n) * K + kk + ch);
    }
    __syncthreads();
    short8 af[2], bfr[4];
#pragma unroll
    for (int mt = 0; mt < 2; ++mt) af[mt] = *(short8*)&As[wave * 32 + mt * 16 + l16][quad * 8];
#pragma unroll
    for (int nt = 0; nt < 4; ++nt) bfr[nt] = *(short8*)&Bs[nt * 16 + l16][quad * 8];
#pragma unroll
    for (int mt = 0; mt < 2; ++mt)
#pragma unroll
      for (int nt = 0; nt < 4; ++nt)
        acc[mt][nt] = __builtin_amdgcn_mfma_f32_16x16x32_bf16(af[mt], bfr[nt], acc[mt][nt], 0, 0, 0);
    __syncthreads();
  }
#pragma unroll
  for (int mt = 0; mt < 2; ++mt) {
#pragma unroll
    for (int reg = 0; reg < 4; ++reg) {
      int r = row0 + wave * 32 + mt * 16 + quad * 4 + reg;
      if (r < M) {
#pragma unroll
        for (int nt = 0; nt < 4; ++nt)
          C[(size_t)r * 256 + col0 + nt * 16 + l16] = f2b(acc[mt][nt][reg]);
      }
    }
  }
}

// ---------------- el/er from bf16 feat. One wave per node.
__global__ __launch_bounds__(256) void compute_elr(const unsigned short* __restrict__ feat,
                                                   const float* __restrict__ al,
                                                   const float* __restrict__ ar,
                                                   float* __restrict__ el,
                                                   float* __restrict__ er, int N) {
  int wave = threadIdx.x >> 6, lane = threadIdx.x & 63;
  int n = blockIdx.x * 4 + wave;
  if (n >= N) return;
  ushort4 fu = *(const ushort4*)(feat + (size_t)n * 256 + lane * 4);
  float4 a = *(const float4*)(al + lane * 4);
  float4 b = *(const float4*)(ar + lane * 4);
  float f0 = b2f(fu.x), f1 = b2f(fu.y), f2 = b2f(fu.z), f3 = b2f(fu.w);
  float sl = f0 * a.x + f1 * a.y + f2 * a.z + f3 * a.w;
  float sr = f0 * b.x + f1 * b.y + f2 * b.z + f3 * b.w;
#pragma unroll
  for (int d = 1; d < 8; d <<= 1) {
    sl += __shfl_xor(sl, d);
    sr += __shfl_xor(sr, d);
  }
  if ((lane & 7) == 0) {
    el[n * 8 + (lane >> 3)] = sl;
    er[n * 8 + (lane >> 3)] = sr;
  }
}

// ---------------- CSR build
__global__ void deg_count(const int* __restrict__ dst, int* __restrict__ deg, int E) {
  int i = blockIdx.x * blockDim.x + threadIdx.x;
  if (i < E) atomicAdd(&deg[dst[i]], 1);
}

__global__ __launch_bounds__(256) void scan1(const int* __restrict__ deg, int* __restrict__ offs,
                                             int* __restrict__ bsums, int n) {
  __shared__ int sh[256];
  int i = blockIdx.x * 256 + threadIdx.x;
  int v = (i < n) ? deg[i] : 0;
  sh[threadIdx.x] = v;
  __syncthreads();
  for (int d = 1; d < 256; d <<= 1) {
    int t = (threadIdx.x >= d) ? sh[threadIdx.x - d] : 0;
    __syncthreads();
    sh[threadIdx.x] += t;
    __syncthreads();
  }
  if (i < n) offs[i + 1] = sh[threadIdx.x];
  if (threadIdx.x == 255) bsums[blockIdx.x] = sh[255];
  if (i == 0) offs[0] = 0;
}

__global__ __launch_bounds__(256) void scan2(int* __restrict__ bsums, int nb) {
  __shared__ int sh[256];
  int t = threadIdx.x;
  int v = (t < nb) ? bsums[t] : 0;
  sh[t] = v;
  __syncthreads();
  for (int d = 1; d < 256; d <<= 1) {
    int tmp = (t >= d) ? sh[t - d] : 0;
    __syncthreads();
    sh[t] += tmp;
    __syncthreads();
  }
  if (t < nb) bsums[t] = (t == 0) ? 0 : sh[t - 1];
}

__global__ __launch_bounds__(256) void scan3(int* __restrict__ offs, const int* __restrict__ bsums,
                                             int n) {
  int i = blockIdx.x * 256 + threadIdx.x;
  if (i < n) offs[i + 1] += bsums[blockIdx.x];
}

__global__ void scatter_edges(const int* __restrict__ src, const int* __restrict__ dst,
                              int* __restrict__ cursor, int* __restrict__ csrc, int E) {
  int i = blockIdx.x * blockDim.x + threadIdx.x;
  if (i < E) {
    int d = dst[i];
    int pos = atomicAdd(&cursor[d], 1);
    csrc[pos] = src[i];
  }
}

// ---------------- GAT aggregation: one wave per dst node. feat/hres/hout bf16.
__global__ __launch_bounds__(256) void gat_agg(const int* __restrict__ offs,
                                               const int* __restrict__ csrc,
                                               const unsigned short* __restrict__ feat,
                                               const float* __restrict__ el,
                                               const float* __restrict__ er,
                                               const float* __restrict__ bias,
                                               const unsigned short* __restrict__ hres,
                                               unsigned short* __restrict__ hout,
                                               float* __restrict__ partial, int N, int mode) {
  __shared__ float psum[4][256];
  const int wave = threadIdx.x >> 6;
  const int lane = threadIdx.x & 63;
  const int hh = lane & 7;    // head for softmax phases
  const int myh = lane >> 3;  // head owning my features
  float4 bvec = *(const float4*)(bias + lane * 4);
  float t0 = 0.f, t1 = 0.f, t2 = 0.f, t3 = 0.f;

  for (int n = blockIdx.x * 4 + wave; n < N; n += gridDim.x * 4) {
    const int o0 = offs[n];
    const int deg = offs[n + 1] - o0;
    const float er_h = er[n * 8 + hh];

    // phase 1: online softmax stats (8 edge-slots x 8 heads)
    float m = -1e30f, ssum = 0.f;
    for (int base = 0; base < deg; base += 8) {
      int idx = base + (lane >> 3);
      if (idx < deg) {
        int s = csrc[o0 + idx];
        float e = lrelu(el[s * 8 + hh] + er_h);
        float mn = fmaxf(m, e);
        ssum = ssum * __expf(m - mn) + __expf(e - mn);
        m = mn;
      }
    }
#pragma unroll
    for (int d = 8; d < 64; d <<= 1) {
      float mo = __shfl_xor(m, d);
      float so = __shfl_xor(ssum, d);
      float mn = fmaxf(m, mo);
      ssum = ssum * __expf(m - mn) + so * __expf(mo - mn);
      m = mn;
    }
    float inv_denom = (ssum > 0.f) ? 1.f / ssum : 0.f;

    // phase 2: weighted gather-accumulate (bf16 feat, 8B/lane/edge)
    float a0 = 0.f, a1 = 0.f, a2 = 0.f, a3 = 0.f;
    for (int base = 0; base < deg; base += 64) {
      int cnt = min(64, deg - base);
      int sreg = (base + lane < deg) ? csrc[o0 + base + lane] : 0;
      for (int j = 0; j < cnt; ++j) {
        int s = __shfl(sreg, j);
        float e = lrelu(el[s * 8 + hh] + er_h);
        float alpha = __expf(e - m) * inv_denom;
        float am = __shfl(alpha, myh);
        ushort4 fu = *(const ushort4*)(feat + (size_t)s * 256 + lane * 4);
        a0 = fmaf(am, b2f(fu.x), a0);
        a1 = fmaf(am, b2f(fu.y), a1);
        a2 = fmaf(am, b2f(fu.z), a2);
        a3 = fmaf(am, b2f(fu.w), a3);
      }
    }

    // epilogue
    float v0 = a0 + bvec.x, v1 = a1 + bvec.y, v2 = a2 + bvec.z, v3 = a3 + bvec.w;
    if (hres) {
      ushort4 r4 = *(const ushort4*)(hres + (size_t)n * 256 + lane * 4);
      v0 += b2f(r4.x); v1 += b2f(r4.y); v2 += b2f(r4.z); v3 += b2f(r4.w);
    }
    v0 = eluf(v0); v1 = eluf(v1); v2 = eluf(v2); v3 = eluf(v3);
    if (mode == 0) {
      ushort4 o;
      o.x = f2b(v0); o.y = f2b(v1); o.z = f2b(v2); o.w = f2b(v3);
      *(ushort4*)(hout + (size_t)n * 256 + lane * 4) = o;
    } else {
      t0 += v0; t1 += v1; t2 += v2; t3 += v3;
    }
  }

  if (mode == 1) {
    psum[wave][lane * 4 + 0] = t0;
    psum[wave][lane * 4 + 1] = t1;
    psum[wave][lane * 4 + 2] = t2;
    psum[wave][lane * 4 + 3] = t3;
    __syncthreads();
    int t = threadIdx.x;
    partial[(size_t)blockIdx.x * 256 + t] = psum[0][t] + psum[1][t] + psum[2][t] + psum[3][t];
  }
}

// ---------------- reduce partial column sums -> s[256]
__global__ __launch_bounds__(256) void reduce_partials(const float* __restrict__ partial,
                                                       float* __restrict__ s, int rows) {
  int t = threadIdx.x;
  float acc = 0.f;
  for (int r = blockIdx.x; r < rows; r += gridDim.x) acc += partial[(size_t)r * 256 + t];
  atomicAdd(&s[t], acc);
}

// ---------------- out[c] = (s/N) @ Wl + bl
__global__ __launch_bounds__(128) void final_linear(const float* __restrict__ s,
                                                    const float* __restrict__ Wl,
                                                    const float* __restrict__ bl,
                                                    float* __restrict__ out, float invN) {
  int c = threadIdx.x;
  float acc = 0.f;
  for (int k = 0; k < 256; ++k) acc = fmaf(s[k], Wl[k * 128 + c], acc);
  out[c] = acc * invN + bl[c];
}

extern "C" void kernel_launch(void* const* d_in, const int* in_sizes, int n_in, void* d_out,
                              int out_size, void* d_ws, size_t ws_size, hipStream_t stream) {
  const float* x  = (const float*)d_in[0];
  const int* src  = (const int*)d_in[1];
  const int* dst  = (const int*)d_in[2];
  const float* W1 = (const float*)d_in[3];
  const float* al1 = (const float*)d_in[4];
  const float* ar1 = (const float*)d_in[5];
  const float* b1 = (const float*)d_in[6];
  const float* W2 = (const float*)d_in[7];
  const float* al2 = (const float*)d_in[8];
  const float* ar2 = (const float*)d_in[9];
  const float* b2 = (const float*)d_in[10];
  const float* Wl = (const float*)d_in[11];
  const float* bl = (const float*)d_in[12];
  float* out = (float*)d_out;

  const int N = in_sizes[0] / 128;  // 50000
  const int E = in_sizes[1];        // 800000
  const int AGG_BLOCKS = 2048;

  // ---- workspace carve (bytes, all 16B-aligned sizes)
  char* w = (char*)d_ws;
  unsigned short* xb    = (unsigned short*)w; w += (size_t)N * 128 * 2;  // 12.8 MB
  unsigned short* featb = (unsigned short*)w; w += (size_t)N * 256 * 2;  // 25.6 MB
  unsigned short* h1b   = (unsigned short*)w; w += (size_t)N * 256 * 2;  // 25.6 MB
  unsigned short* W1t   = (unsigned short*)w; w += (size_t)256 * 128 * 2;
  unsigned short* W2t   = (unsigned short*)w; w += (size_t)256 * 256 * 2;
  float* el = (float*)w;        w += (size_t)N * 8 * 4;
  float* er = (float*)w;        w += (size_t)N * 8 * 4;
  int* offs = (int*)w;          w += (size_t)(N + 64) * 4;
  int* deg = (int*)w;           w += (size_t)N * 4;
  int* cursor = (int*)w;        w += (size_t)N * 4;
  int* csrc = (int*)w;          w += (size_t)E * 4;
  int* bsums = (int*)w;         w += 256 * 4;
  float* partial = (float*)w;   w += (size_t)AGG_BLOCKS * 256 * 4;
  float* svec = (float*)w;      w += 256 * 4;

  const int nb = (N + 255) / 256;
  const int eb = (E + 255) / 256;
  const int gmb = (N + BM - 1) / BM;  // 391
  const int nodeb = (N + 3) / 4;

  // ---- CSR build (dst-indexed) + zero init
  hipMemsetAsync(deg, 0, (size_t)N * 4, stream);
  hipMemsetAsync(svec, 0, 256 * 4, stream);
  deg_count<<<eb, 256, 0, stream>>>(dst, deg, E);
  scan1<<<nb, 256, 0, stream>>>(deg, offs, bsums, N);
  scan2<<<1, 256, 0, stream>>>(bsums, nb);
  scan3<<<nb, 256, 0, stream>>>(offs, bsums, N);
  hipMemcpyAsync(cursor, offs, (size_t)N * 4, hipMemcpyDeviceToDevice, stream);
  scatter_edges<<<eb, 256, 0, stream>>>(src, dst, cursor, csrc, E);

  // ---- casts
  cast_bf16_vec<<<(N * 128 / 4 + 255) / 256, 256, 0, stream>>>(x, xb, N * 128 / 4);
  cast_w_t<<<(128 * 256 + 255) / 256, 256, 0, stream>>>(W1, W1t, 128);
  cast_w_t<<<(256 * 256 + 255) / 256, 256, 0, stream>>>(W2, W2t, 256);

  // ---- layer 1
  gemm_bf16<<<dim3(gmb, 4), 256, 0, stream>>>(xb, W1t, featb, N, 128);
  compute_elr<<<nodeb, 256, 0, stream>>>(featb, al1, ar1, el, er, N);
  gat_agg<<<AGG_BLOCKS, 256, 0, stream>>>(offs, csrc, featb, el, er, b1, nullptr, h1b, nullptr, N, 0);

  // ---- layer 2
  gemm_bf16<<<dim3(gmb, 4), 256, 0, stream>>>(h1b, W2t, featb, N, 256);
  compute_elr<<<nodeb, 256, 0, stream>>>(featb, al2, ar2, el, er, N);
  gat_agg<<<AGG_BLOCKS, 256, 0, stream>>>(offs, csrc, featb, el, er, b2, h1b, nullptr, partial, N, 1);

  // ---- mean over nodes, then final linear
  reduce_partials<<<64, 256, 0, stream>>>(partial, svec, AGG_BLOCKS);
  final_linear<<<1, 128, 0, stream>>>(svec, Wl, bl, out, 1.0f / (float)N);
}